// Round 7
// baseline (274.984 us; speedup 1.0000x reference)
//
#include <hip/hip_runtime.h>
#include <cstdint>

#define B_   32
#define C_   512
#define N_   1024
#define G_   32
#define CG_  16

typedef unsigned short u16;

static constexpr float kEps = 1e-5f;
// 512^-0.5 * log2(e): S-GEMM writes scores in log2-domain; softmax base-2 == base-e.
static constexpr float kLog2Scale = 0.06375871752987579f;

using f32x4  = __attribute__((ext_vector_type(4))) float;
using short8 = __attribute__((ext_vector_type(8))) short;

__device__ __forceinline__ u16 f2bf(float f) {
  uint32_t u = __builtin_bit_cast(uint32_t, f);
  u += 0x7fffu + ((u >> 16) & 1u);   // RNE
  return (u16)(u >> 16);
}
__device__ __forceinline__ float bf2f(u16 h) {
  return __builtin_bit_cast(float, (uint32_t)h << 16);
}

// async global->LDS, 16B per lane. LDS dest is wave-uniform base (HW adds lane*16).
__device__ __forceinline__ void gload16(const void* g, void* lds) {
  __builtin_amdgcn_global_load_lds(
      (__attribute__((address_space(1))) void*)(uintptr_t)g,
      (__attribute__((address_space(3))) void*)(uint32_t)(uintptr_t)lds,
      16, 0, 0);
}

// bijective XCD-chunked remap (m204): contiguous logical chunk per XCD.
__device__ __forceinline__ uint3 remap_xcd() {
  const int gx = gridDim.x, gy = gridDim.y, gz = gridDim.z;
  const int nwg = gx * gy * gz;
  const int lin = blockIdx.x + gx * (blockIdx.y + gy * blockIdx.z);
  const int q = nwg >> 3, r = nwg & 7;
  const int xcd = lin & 7, pos = lin >> 3;
  int nid = (xcd < r ? xcd * (q + 1) : r * (q + 1) + (xcd - r) * q) + pos;
  uint3 o;
  o.x = nid % gx; nid /= gx;
  o.y = nid % gy; o.z = nid / gy;
  return o;
}

// ---------------- weights: Wt[m][o][c] = bf16(W[c][o]), LDS tile transpose ----------------
__global__ __launch_bounds__(256) void wt_kernel(
    const float* __restrict__ Wq, const float* __restrict__ Wk,
    const float* __restrict__ Wv, const float* __restrict__ Wn,
    u16* __restrict__ Wt) {
  __shared__ float tile[64][65];
  const int m = blockIdx.z;
  const int c0 = blockIdx.y * 64, o0 = blockIdx.x * 64;
  const float* W = (m == 0) ? Wq : (m == 1) ? Wk : (m == 2) ? Wv : Wn;
  const int tx = threadIdx.x & 15, ty = threadIdx.x >> 4;
#pragma unroll
  for (int rr = 0; rr < 64; rr += 16) {
    const int c = c0 + ty + rr;
    const float4 v = *(const float4*)(W + (size_t)c * 512 + o0 + tx * 4);
    tile[ty + rr][tx * 4 + 0] = v.x;
    tile[ty + rr][tx * 4 + 1] = v.y;
    tile[ty + rr][tx * 4 + 2] = v.z;
    tile[ty + rr][tx * 4 + 3] = v.w;
  }
  __syncthreads();
#pragma unroll
  for (int rr = 0; rr < 64; rr += 16) {
    const int o = o0 + ty + rr;
    ushort4 st;
    st.x = f2bf(tile[tx * 4 + 0][ty + rr]);
    st.y = f2bf(tile[tx * 4 + 1][ty + rr]);
    st.z = f2bf(tile[tx * 4 + 2][ty + rr]);
    st.w = f2bf(tile[tx * 4 + 3][ty + rr]);
    *(ushort4*)(Wt + (size_t)m * 262144 + (size_t)o * 512 + c0 + tx * 4) = st;
  }
}

// ---------------- fused groupnorm: one pass over x, stats + normalize + transpose ------
__global__ __launch_bounds__(256) void gn_fused(const float* __restrict__ x,
                                                u16* __restrict__ Hn) {
  __shared__ float lds[16 * 1028];
  __shared__ float red[10];
  const int bg = blockIdx.x, b = bg >> 5, g = bg & 31;
  const int t = threadIdx.x;
  const float4* p4 = (const float4*)(x + (size_t)bg * 16384);
  float s = 0.f, s2 = 0.f;
  for (int i = t; i < 4096; i += 256) {
    const float4 v = p4[i];
    const int e = i * 4, ic = e >> 10, n = e & 1023;
    *(float4*)(lds + ic * 1028 + n) = v;
    s  += v.x + v.y + v.z + v.w;
    s2 += v.x * v.x + v.y * v.y + v.z * v.z + v.w * v.w;
  }
#pragma unroll
  for (int o = 32; o; o >>= 1) { s += __shfl_xor(s, o); s2 += __shfl_xor(s2, o); }
  const int lane = t & 63, w = t >> 6;
  if (lane == 0) { red[w] = s; red[4 + w] = s2; }
  __syncthreads();
  if (t == 0) {
    s  = red[0] + red[1] + red[2] + red[3];
    s2 = red[4] + red[5] + red[6] + red[7];
    const float inv = 1.0f / 16384.0f;
    const float mean = s * inv;
    const float var  = s2 * inv - mean * mean;
    red[8] = mean;
    red[9] = rsqrtf(var + kEps);
  }
  __syncthreads();
  const float mean = red[8], rstd = red[9];
#pragma unroll
  for (int r = 0; r < 4; ++r) {
    const int n = t + 256 * r;
    ushort o8[16];
#pragma unroll
    for (int ic = 0; ic < 16; ++ic)
      o8[ic] = f2bf((lds[ic * 1028 + n] - mean) * rstd);
    u16* dst = Hn + ((size_t)(b * N_ + n)) * C_ + g * 16;
#pragma unroll
    for (int q = 0; q < 4; ++q) {
      ushort4 st; st.x = o8[q*4]; st.y = o8[q*4+1]; st.z = o8[q*4+2]; st.w = o8[q*4+3];
      *(ushort4*)(dst + q * 4) = st;
    }
  }
}

// ---------------- GEMM core: 256x256 tile, BK=64, 8 waves (2Mx4N), dbuf LDS,
// 4 phases/K-tile with register-pipelined fragment reads, counted lgkmcnt, XOR-swizzle.
// SM=true: B-fragments are log2-domain scores; apply exp2 in-register before MFMA and
// accumulate per-lane partial row-sums in psum[4] (softmax fused into the GEMM).
#define LDA_(D, BASE, MH, PC)                                                   \
  _Pragma("unroll")                                                             \
  for (int i_ = 0; i_ < 4; ++i_)                                                \
    D[i_] = *(const short8*)((BASE) + (wm * 128 + (MH) * 64 + i_ * 16 + arow) * 128 + (PC));
#define LDB_(D, BASE, PC)                                                       \
  _Pragma("unroll")                                                             \
  for (int j_ = 0; j_ < 4; ++j_)                                                \
    D[j_] = *(const short8*)((BASE) + (wn * 64 + j_ * 16 + arow) * 128 + (PC));
#define MM_(ACC, AA, BB)                                                        \
  __builtin_amdgcn_s_setprio(1);                                                \
  _Pragma("unroll")                                                             \
  for (int i_ = 0; i_ < 4; ++i_)                                                \
    _Pragma("unroll")                                                           \
    for (int j_ = 0; j_ < 4; ++j_)                                              \
      ACC[i_][j_] = __builtin_amdgcn_mfma_f32_16x16x32_bf16(AA[i_], BB[j_], ACC[i_][j_], 0, 0, 0); \
  __builtin_amdgcn_s_setprio(0);
// exp2 each bf16 score, track row-sum, repack to bf16 P (unnormalized, <= 2^rowmax).
#define XF_(BB)                                                                 \
  _Pragma("unroll")                                                             \
  for (int j_ = 0; j_ < 4; ++j_) {                                              \
    short8 f_ = BB[j_];                                                         \
    _Pragma("unroll")                                                           \
    for (int v_ = 0; v_ < 8; ++v_) {                                            \
      const float p_ = __builtin_exp2f(bf2f((u16)f_[v_]));                      \
      psum[j_] += p_;                                                           \
      f_[v_] = (short)f2bf(p_);                                                 \
    }                                                                           \
    BB[j_] = f_;                                                                \
  }

template <bool SM>
__device__ __forceinline__ void gemm_core256(
    const u16* __restrict__ A, const u16* __restrict__ B,
    int Ktot, int m0, int n0,
    u16* Alds, u16* Blds, f32x4 acc0[4][4], f32x4 acc1[4][4], float* psum) {
  const int tid = threadIdx.x, lane = tid & 63, wid = tid >> 6;
  const int wm = wid >> 2, wn = wid & 3;

  const int sr  = lane >> 3;
  const int scb = (lane & 7) ^ sr;             // pre-swizzled source 16B-block
  const u16* Ag = A + (size_t)(m0 + wid * 32 + sr) * Ktot + scb * 8;
  const u16* Bg = B + (size_t)(n0 + wid * 32 + sr) * Ktot + scb * 8;
  char* Al = (char*)Alds + wid * 4096;
  char* Bl = (char*)Blds + wid * 4096;
  const long long r8 = (long long)8 * Ktot;    // 8 rows in elements

  const int arow = lane & 15, g4 = lane >> 4, rx = lane & 7;
  const int pc0 = (g4 ^ rx) * 16;              // kk0 swizzled phys byte col
  const int pc1 = ((4 + g4) ^ rx) * 16;        // kk1
  const int nt = Ktot >> 6;

  // prologue: stage tile 0 into buf 0, drain, preload ph0 fragments
#pragma unroll
  for (int g = 0; g < 4; ++g) {
    gload16(Ag + g * r8, Al + g * 1024);
    gload16(Bg + g * r8, Bl + g * 1024);
  }
  asm volatile("s_waitcnt vmcnt(0)" ::: "memory");
  __builtin_amdgcn_s_barrier();
  short8 aX[4], aY[4], bX[4], bY[4];
  LDA_(aX, (const char*)Alds, 0, pc0);
  LDB_(bX, (const char*)Blds, pc0);

  for (int t = 0; t < nt; ++t) {
    const int cur = t & 1;
    const char* Ab = (const char*)Alds + cur * 32768;
    const char* Bb = (const char*)Blds + cur * 32768;
    const char* An = (const char*)Alds + (cur ^ 1) * 32768;
    const char* Bn = (const char*)Blds + (cur ^ 1) * 32768;
    char* Aln = Al + (cur ^ 1) * 32768;
    char* Bln = Bl + (cur ^ 1) * 32768;
    const bool nx = (t + 1 < nt);
    const long long ko = (long long)(t + 1) * 64;

    // ---- ph0: MFMA(aX,bX)->acc0 ; stage next-B ; prefetch aY (ph1)
    if (nx) {
#pragma unroll
      for (int g = 0; g < 4; ++g) gload16(Bg + ko + g * r8, Bln + g * 1024);
    }
    LDA_(aY, Ab, 1, pc0);
    asm volatile("s_waitcnt lgkmcnt(4)" ::: "memory");   // aX,bX done; aY in flight
    __builtin_amdgcn_sched_barrier(0);
    __builtin_amdgcn_s_barrier();
    if constexpr (SM) { XF_(bX); }                       // once per tile, before first use
    MM_(acc0, aX, bX);

    // ---- ph1: MFMA(aY,bX)->acc1 ; stage next-A ; prefetch aX,bY (ph2)
    if (nx) {
#pragma unroll
      for (int g = 0; g < 4; ++g) gload16(Ag + ko + g * r8, Aln + g * 1024);
    }
    LDA_(aX, Ab, 0, pc1);
    LDB_(bY, Bb, pc1);
    asm volatile("s_waitcnt lgkmcnt(8)" ::: "memory");   // aY done; aX,bY in flight
    __builtin_amdgcn_sched_barrier(0);
    __builtin_amdgcn_s_barrier();
    MM_(acc1, aY, bX);

    // ---- ph2: MFMA(aX,bY)->acc0 ; prefetch aY (ph3)
    LDA_(aY, Ab, 1, pc1);
    asm volatile("s_waitcnt lgkmcnt(4)" ::: "memory");   // aX,bY done; aY in flight
    __builtin_amdgcn_sched_barrier(0);
    __builtin_amdgcn_s_barrier();
    if constexpr (SM) { XF_(bY); }
    MM_(acc0, aX, bY);

    // ---- ph3: boundary sync, then MFMA(aY,bY)->acc1 with next-tile reads under it
    asm volatile("s_waitcnt lgkmcnt(0)" ::: "memory");   // aY done (all reads drained)
    if (nx) {
      asm volatile("s_waitcnt vmcnt(0)" ::: "memory");   // own 8 stage loads landed
    }
    __builtin_amdgcn_sched_barrier(0);
    __builtin_amdgcn_s_barrier();                        // ALL waves: reads drained + stages landed
    if (nx) {
      LDA_(aX, An, 0, pc0);                              // next-tile ph0 frags, hide under MFMA
      LDB_(bX, Bn, pc0);
    }
    MM_(acc1, aY, bY);
  }
}

// D fragment mapping (m89-verified): col = lane&15, row = (lane>>4)*4 + reg.
__global__ __launch_bounds__(512, 2) void gemm_bt(
    const u16* __restrict__ A, long long sAz,
    const u16* __restrict__ B, long long sBz,
    u16* __restrict__ Out, long long sOz,
    int Ktot, int LDC, float scale,
    const float* __restrict__ bias, int biasMode) {
  __shared__ u16 Alds[2 * 256 * 64];
  __shared__ u16 Blds[2 * 256 * 64];
  const uint3 bid = remap_xcd();
  const int z = bid.z;
  A += (size_t)z * sAz;
  B += (size_t)z * sBz;
  u16* O = Out + (size_t)z * sOz;
  const int m0 = bid.y * 256, n0 = bid.x * 256;
  f32x4 acc0[4][4] = {};
  f32x4 acc1[4][4] = {};
  gemm_core256<false>(A, B, Ktot, m0, n0, Alds, Blds, acc0, acc1, nullptr);

  const int lane = threadIdx.x & 63, wid = threadIdx.x >> 6;
  const int wm = wid >> 2, wn = wid & 3;
#pragma unroll
  for (int i = 0; i < 8; ++i) {
    const int rowg = m0 + wm * 128 + i * 16 + ((lane >> 4) * 4);
    float b0 = 0.f, b1 = 0.f, b2 = 0.f, b3 = 0.f;
    if (biasMode == 1) {
      const float4 bv = *(const float4*)(bias + rowg);
      b0 = bv.x; b1 = bv.y; b2 = bv.z; b3 = bv.w;
    }
#pragma unroll
    for (int j = 0; j < 4; ++j) {
      const int colg = n0 + wn * 64 + j * 16 + (lane & 15);
      const float bc = (biasMode == 2) ? bias[colg] : 0.0f;
      const f32x4 v = (i < 4) ? acc0[i][j] : acc1[i - 4][j];
      ushort4 st;
      st.x = f2bf(v[0] * scale + b0 + bc);
      st.y = f2bf(v[1] * scale + b1 + bc);
      st.z = f2bf(v[2] * scale + b2 + bc);
      st.w = f2bf(v[3] * scale + b3 + bc);
      *(ushort4*)(O + (size_t)colg * LDC + rowg) = st;
    }
  }
}

// fused QKV: A = Wt rows o in [0,1536) (Wq|Wk|Wv stacked), B = Hn[z], K=512.
__global__ __launch_bounds__(512, 2) void gemm_qkv(
    const u16* __restrict__ Wt, const u16* __restrict__ Hn,
    u16* __restrict__ Qb, u16* __restrict__ Kb, u16* __restrict__ Vt,
    const float* __restrict__ bq, const float* __restrict__ bk,
    const float* __restrict__ bv) {
  __shared__ u16 Alds[2 * 256 * 64];
  __shared__ u16 Blds[2 * 256 * 64];
  const uint3 bid = remap_xcd();
  const int z = bid.z;
  const u16* B = Hn + (size_t)z * ((size_t)N_ * C_);
  const int m0 = bid.y * 256;    // o in [0,1536)
  const int n0 = bid.x * 256;    // n
  f32x4 acc0[4][4] = {};
  f32x4 acc1[4][4] = {};
  gemm_core256<false>(Wt, B, 512, m0, n0, Alds, Blds, acc0, acc1, nullptr);

  const int lane = threadIdx.x & 63, wid = threadIdx.x >> 6;
  const int wm = wid >> 2, wn = wid & 3;
  const int mat = m0 >> 9;       // 0:Q 1:K 2:V (block-uniform)
  const float* bias = (mat == 0) ? bq : (mat == 1) ? bk : bv;
  u16* O  = ((mat == 0) ? Qb : Kb) + (size_t)z * ((size_t)N_ * C_);
  u16* Vz = Vt + (size_t)z * ((size_t)N_ * C_);
#pragma unroll
  for (int i = 0; i < 8; ++i) {
    const int rowg = m0 + wm * 128 + i * 16 + ((lane >> 4) * 4);
    const int o = rowg & 511;
    const float4 bvv = *(const float4*)(bias + o);
#pragma unroll
    for (int j = 0; j < 4; ++j) {
      const int colg = n0 + wn * 64 + j * 16 + (lane & 15);
      const f32x4 v = (i < 4) ? acc0[i][j] : acc1[i - 4][j];
      if (mat < 2) {
        ushort4 st;
        st.x = f2bf(v[0] + bvv.x);
        st.y = f2bf(v[1] + bvv.y);
        st.z = f2bf(v[2] + bvv.z);
        st.w = f2bf(v[3] + bvv.w);
        *(ushort4*)(O + (size_t)colg * 512 + o) = st;
      } else {
        Vz[(size_t)(o + 0) * N_ + colg] = f2bf(v[0] + bvv.x);
        Vz[(size_t)(o + 1) * N_ + colg] = f2bf(v[1] + bvv.y);
        Vz[(size_t)(o + 2) * N_ + colg] = f2bf(v[2] + bvv.z);
        Vz[(size_t)(o + 3) * N_ + colg] = f2bf(v[3] + bvv.w);
      }
    }
  }
}

// fused PV + softmax: A = Vt[z] (rows c, ld 1024), B = P[z] (rows n, raw log2-scores,
// ld 1024 = softmax axis = K-dim, fully inside this block's K-loop). Core exp2's the
// B-frags and tracks per-lane partial row-sums; epilogue reduces + normalizes.
__global__ __launch_bounds__(512, 2) void gemm_pv(
    const u16* __restrict__ Vt, const u16* __restrict__ P,
    u16* __restrict__ H2) {
  __shared__ u16 Alds[2 * 256 * 64];
  __shared__ u16 Blds[2 * 256 * 64];
  const uint3 bid = remap_xcd();
  const int z = bid.z;
  const u16* A = Vt + (size_t)z * ((size_t)N_ * C_);
  const u16* B = P  + (size_t)z * ((size_t)N_ * N_);
  u16*       O = H2 + (size_t)z * ((size_t)N_ * C_);
  const int m0 = bid.y * 256, n0 = bid.x * 256;   // m0: c, n0: n
  f32x4 acc0[4][4] = {};
  f32x4 acc1[4][4] = {};
  float psum[4] = {0.f, 0.f, 0.f, 0.f};
  gemm_core256<true>(A, B, 1024, m0, n0, Alds, Blds, acc0, acc1, psum);

  const int lane = threadIdx.x & 63, wid = threadIdx.x >> 6;
  const int wm = wid >> 2, wn = wid & 3;
  // full row-sum: 4 lanes (xor 16/32) hold disjoint k-chunk partials of the same n-row
  float inv[4];
#pragma unroll
  for (int j = 0; j < 4; ++j) {
    float r = psum[j];
    r += __shfl_xor(r, 16);
    r += __shfl_xor(r, 32);
    inv[j] = 1.0f / r;
  }
#pragma unroll
  for (int i = 0; i < 8; ++i) {
    const int rowg = m0 + wm * 128 + i * 16 + ((lane >> 4) * 4);   // c
#pragma unroll
    for (int j = 0; j < 4; ++j) {
      const int colg = n0 + wn * 64 + j * 16 + (lane & 15);        // n
      const f32x4 v = (i < 4) ? acc0[i][j] : acc1[i - 4][j];
      ushort4 st;
      st.x = f2bf(v[0] * inv[j]);
      st.y = f2bf(v[1] * inv[j]);
      st.z = f2bf(v[2] * inv[j]);
      st.w = f2bf(v[3] * inv[j]);
      *(ushort4*)(O + (size_t)colg * 512 + rowg) = st;
    }
  }
}

// final: D[n][o] = sum_c H2[n][c]*Wnt[o][c]; out[b][o][n] = x + D + bn[o]  (fp32)
__global__ __launch_bounds__(512, 2) void gemm_bt_final(
    const u16* __restrict__ A, const u16* __restrict__ Bw,
    const float* __restrict__ x, const float* __restrict__ bn,
    float* __restrict__ Out, int Ktot) {
  __shared__ u16 Alds[2 * 256 * 64];
  __shared__ u16 Blds[2 * 256 * 64];
  const uint3 bid = remap_xcd();
  const int z = bid.z;
  const u16*   Ab = A + (size_t)z * ((size_t)N_ * C_);
  const float* xb = x + (size_t)z * ((size_t)C_ * N_);
  float*       Ob = Out + (size_t)z * ((size_t)C_ * N_);
  const int m0 = bid.y * 256, n0 = bid.x * 256;
  f32x4 acc0[4][4] = {};
  f32x4 acc1[4][4] = {};
  gemm_core256<false>(Ab, Bw, Ktot, m0, n0, Alds, Blds, acc0, acc1, nullptr);

  const int lane = threadIdx.x & 63, wid = threadIdx.x >> 6;
  const int wm = wid >> 2, wn = wid & 3;
#pragma unroll
  for (int i = 0; i < 8; ++i) {
    const int rowg = m0 + wm * 128 + i * 16 + ((lane >> 4) * 4);   // n
#pragma unroll
    for (int j = 0; j < 4; ++j) {
      const int colg = n0 + wn * 64 + j * 16 + (lane & 15);        // o
      const float bc = bn[colg];
      const size_t off = (size_t)colg * N_ + rowg;
      const float4 xv = *(const float4*)(xb + off);
      const f32x4 v = (i < 4) ? acc0[i][j] : acc1[i - 4][j];
      float4 ov;
      ov.x = xv.x + v[0] + bc;
      ov.y = xv.y + v[1] + bc;
      ov.z = xv.z + v[2] + bc;
      ov.w = xv.w + v[3] + bc;
      *(float4*)(Ob + off) = ov;
    }
  }
}

__global__ void sentinel_kernel(float* out, int n, float v) {
  const int i = blockIdx.x * blockDim.x + threadIdx.x;
  if (i < n) out[i] = v;
}

extern "C" void kernel_launch(void* const* d_in, const int* in_sizes, int n_in,
                              void* d_out, int out_size, void* d_ws, size_t ws_size,
                              hipStream_t stream) {
  const float* x  = (const float*)d_in[0];
  const float* Wq = (const float*)d_in[1];
  const float* bq = (const float*)d_in[2];
  const float* Wk = (const float*)d_in[3];
  const float* bk = (const float*)d_in[4];
  const float* Wv = (const float*)d_in[5];
  const float* bv = (const float*)d_in[6];
  const float* Wn = (const float*)d_in[7];
  const float* bn = (const float*)d_in[8];
  float* out = (float*)d_out;

  char* ws = (char*)d_ws;
  size_t off = 0;
  u16* Wt = (u16*)(ws + off);      off += (size_t)4 * 512 * 512 * 2;   // bf16 W^T x4 (Q|K|V|N)
  const size_t bnc = (size_t)B_ * N_ * C_;
  u16* Hn = (u16*)(ws + off); off += bnc * 2;          // [b][n][c]
  u16* Qb = (u16*)(ws + off); off += bnc * 2;          // [b][n][c]
  u16* Kb = (u16*)(ws + off); off += bnc * 2;          // [b][m][c]
  u16* Vt = (u16*)(ws + off); off += bnc * 2;          // [b][c][m]
  u16* P  = (u16*)(ws + off); off += (size_t)B_ * N_ * N_ * 2;  // [b][n][m] raw log2-scores
  u16* H2 = (u16*)(ws + off); off += bnc * 2;          // [b][n][c]

  if (ws_size < off) {
    const float v = 1.0e6f + (float)(ws_size >> 20);   // absmax ~ 1e6+MB -> diagnosable
    sentinel_kernel<<<(out_size + 255) / 256, 256, 0, stream>>>(out, out_size, v);
    return;
  }

  wt_kernel<<<dim3(8, 8, 4), 256, 0, stream>>>(Wq, Wk, Wv, Wn, Wt);
  gn_fused<<<B_ * G_, 256, 0, stream>>>(x, Hn);

  const long long sNC = (long long)N_ * C_;
  const long long sNN = (long long)N_ * N_;
  // fused QKV: o-rows [0,1536) of Wt vs Hn; writes Qb[n][o], Kb[n][o], Vt[o][n]+biases
  gemm_qkv<<<dim3(4, 6, B_), 512, 0, stream>>>(Wt, Hn, Qb, Kb, Vt, bq, bk, bv);
  // S[n][m] in log2-domain: A=K (rows m), B=Q (rows n), K-dim=512, scale=1/sqrt(512)*log2e
  gemm_bt<<<dim3(4, 4, B_), 512, 0, stream>>>(Kb, sNC, Qb, sNC, P, sNN, 512, 1024, kLog2Scale, nullptr, 0);
  // fused softmax+PV: H2[n][c] = softmax-row(P[n][:]) . V
  gemm_pv<<<dim3(4, 2, B_), 512, 0, stream>>>(Vt, P, H2);
  // out[o][n] = x + H2·Wn^T + bn
  gemm_bt_final<<<dim3(2, 4, B_), 512, 0, stream>>>(H2, Wt + 3 * 262144, x, bn, out, 512);
}

// Round 8
// 239.138 us; speedup vs baseline: 1.1499x; 1.1499x over previous
//
#include <hip/hip_runtime.h>
#include <cstdint>

#define B_   32
#define C_   512
#define N_   1024
#define G_   32
#define CG_  16

typedef unsigned short u16;

static constexpr float kEps = 1e-5f;
// 512^-0.5 * log2(e): softmax computed base-2 (exp2), base-change invariant.
static constexpr float kLog2Scale = 0.06375871752987579f;

using f32x4  = __attribute__((ext_vector_type(4))) float;
using short8 = __attribute__((ext_vector_type(8))) short;

__device__ __forceinline__ u16 f2bf(float f) {
  uint32_t u = __builtin_bit_cast(uint32_t, f);
  u += 0x7fffu + ((u >> 16) & 1u);   // RNE
  return (u16)(u >> 16);
}
__device__ __forceinline__ float bf2f(u16 h) {
  return __builtin_bit_cast(float, (uint32_t)h << 16);
}

// async global->LDS, 16B per lane. LDS dest is wave-uniform base (HW adds lane*16).
__device__ __forceinline__ void gload16(const void* g, void* lds) {
  __builtin_amdgcn_global_load_lds(
      (__attribute__((address_space(1))) void*)(uintptr_t)g,
      (__attribute__((address_space(3))) void*)(uint32_t)(uintptr_t)lds,
      16, 0, 0);
}

// bijective XCD-chunked remap (m204): contiguous logical chunk per XCD.
__device__ __forceinline__ uint3 remap_xcd() {
  const int gx = gridDim.x, gy = gridDim.y, gz = gridDim.z;
  const int nwg = gx * gy * gz;
  const int lin = blockIdx.x + gx * (blockIdx.y + gy * blockIdx.z);
  const int q = nwg >> 3, r = nwg & 7;
  const int xcd = lin & 7, pos = lin >> 3;
  int nid = (xcd < r ? xcd * (q + 1) : r * (q + 1) + (xcd - r) * q) + pos;
  uint3 o;
  o.x = nid % gx; nid /= gx;
  o.y = nid % gy; o.z = nid / gy;
  return o;
}

// ---------------- weights: Wt[m][o][c] = bf16(W[c][o]), LDS tile transpose ----------------
__global__ __launch_bounds__(256) void wt_kernel(
    const float* __restrict__ Wq, const float* __restrict__ Wk,
    const float* __restrict__ Wv, const float* __restrict__ Wn,
    u16* __restrict__ Wt) {
  __shared__ float tile[64][65];
  const int m = blockIdx.z;
  const int c0 = blockIdx.y * 64, o0 = blockIdx.x * 64;
  const float* W = (m == 0) ? Wq : (m == 1) ? Wk : (m == 2) ? Wv : Wn;
  const int tx = threadIdx.x & 15, ty = threadIdx.x >> 4;
#pragma unroll
  for (int rr = 0; rr < 64; rr += 16) {
    const int c = c0 + ty + rr;
    const float4 v = *(const float4*)(W + (size_t)c * 512 + o0 + tx * 4);
    tile[ty + rr][tx * 4 + 0] = v.x;
    tile[ty + rr][tx * 4 + 1] = v.y;
    tile[ty + rr][tx * 4 + 2] = v.z;
    tile[ty + rr][tx * 4 + 3] = v.w;
  }
  __syncthreads();
#pragma unroll
  for (int rr = 0; rr < 64; rr += 16) {
    const int o = o0 + ty + rr;
    ushort4 st;
    st.x = f2bf(tile[tx * 4 + 0][ty + rr]);
    st.y = f2bf(tile[tx * 4 + 1][ty + rr]);
    st.z = f2bf(tile[tx * 4 + 2][ty + rr]);
    st.w = f2bf(tile[tx * 4 + 3][ty + rr]);
    *(ushort4*)(Wt + (size_t)m * 262144 + (size_t)o * 512 + c0 + tx * 4) = st;
  }
}

// ---------------- fused groupnorm: one pass over x, stats + normalize + transpose ------
__global__ __launch_bounds__(256) void gn_fused(const float* __restrict__ x,
                                                u16* __restrict__ Hn) {
  __shared__ float lds[16 * 1028];
  __shared__ float red[10];
  const int bg = blockIdx.x, b = bg >> 5, g = bg & 31;
  const int t = threadIdx.x;
  const float4* p4 = (const float4*)(x + (size_t)bg * 16384);
  float s = 0.f, s2 = 0.f;
  for (int i = t; i < 4096; i += 256) {
    const float4 v = p4[i];
    const int e = i * 4, ic = e >> 10, n = e & 1023;
    *(float4*)(lds + ic * 1028 + n) = v;
    s  += v.x + v.y + v.z + v.w;
    s2 += v.x * v.x + v.y * v.y + v.z * v.z + v.w * v.w;
  }
#pragma unroll
  for (int o = 32; o; o >>= 1) { s += __shfl_xor(s, o); s2 += __shfl_xor(s2, o); }
  const int lane = t & 63, w = t >> 6;
  if (lane == 0) { red[w] = s; red[4 + w] = s2; }
  __syncthreads();
  if (t == 0) {
    s  = red[0] + red[1] + red[2] + red[3];
    s2 = red[4] + red[5] + red[6] + red[7];
    const float inv = 1.0f / 16384.0f;
    const float mean = s * inv;
    const float var  = s2 * inv - mean * mean;
    red[8] = mean;
    red[9] = rsqrtf(var + kEps);
  }
  __syncthreads();
  const float mean = red[8], rstd = red[9];
#pragma unroll
  for (int r = 0; r < 4; ++r) {
    const int n = t + 256 * r;
    ushort o8[16];
#pragma unroll
    for (int ic = 0; ic < 16; ++ic)
      o8[ic] = f2bf((lds[ic * 1028 + n] - mean) * rstd);
    u16* dst = Hn + ((size_t)(b * N_ + n)) * C_ + g * 16;
#pragma unroll
    for (int q = 0; q < 4; ++q) {
      ushort4 st; st.x = o8[q*4]; st.y = o8[q*4+1]; st.z = o8[q*4+2]; st.w = o8[q*4+3];
      *(ushort4*)(dst + q * 4) = st;
    }
  }
}

// ---------------- GEMM core: 256x256 tile, BK=64, 8 waves (2Mx4N), dbuf LDS,
// 4 phases/K-tile with register-pipelined fragment reads, counted lgkmcnt, XOR-swizzle.
#define LDA_(D, BASE, MH, PC)                                                   \
  _Pragma("unroll")                                                             \
  for (int i_ = 0; i_ < 4; ++i_)                                                \
    D[i_] = *(const short8*)((BASE) + (wm * 128 + (MH) * 64 + i_ * 16 + arow) * 128 + (PC));
#define LDB_(D, BASE, PC)                                                       \
  _Pragma("unroll")                                                             \
  for (int j_ = 0; j_ < 4; ++j_)                                                \
    D[j_] = *(const short8*)((BASE) + (wn * 64 + j_ * 16 + arow) * 128 + (PC));
#define MM_(ACC, AA, BB)                                                        \
  __builtin_amdgcn_s_setprio(1);                                                \
  _Pragma("unroll")                                                             \
  for (int i_ = 0; i_ < 4; ++i_)                                                \
    _Pragma("unroll")                                                           \
    for (int j_ = 0; j_ < 4; ++j_)                                              \
      ACC[i_][j_] = __builtin_amdgcn_mfma_f32_16x16x32_bf16(AA[i_], BB[j_], ACC[i_][j_], 0, 0, 0); \
  __builtin_amdgcn_s_setprio(0);

__device__ __forceinline__ void gemm_core256(
    const u16* __restrict__ A, const u16* __restrict__ B,
    int Ktot, int m0, int n0,
    u16* Alds, u16* Blds, f32x4 acc0[4][4], f32x4 acc1[4][4]) {
  const int tid = threadIdx.x, lane = tid & 63, wid = tid >> 6;
  const int wm = wid >> 2, wn = wid & 3;

  const int sr  = lane >> 3;
  const int scb = (lane & 7) ^ sr;             // pre-swizzled source 16B-block
  const u16* Ag = A + (size_t)(m0 + wid * 32 + sr) * Ktot + scb * 8;
  const u16* Bg = B + (size_t)(n0 + wid * 32 + sr) * Ktot + scb * 8;
  char* Al = (char*)Alds + wid * 4096;
  char* Bl = (char*)Blds + wid * 4096;
  const long long r8 = (long long)8 * Ktot;    // 8 rows in elements

  const int arow = lane & 15, g4 = lane >> 4, rx = lane & 7;
  const int pc0 = (g4 ^ rx) * 16;              // kk0 swizzled phys byte col
  const int pc1 = ((4 + g4) ^ rx) * 16;        // kk1
  const int nt = Ktot >> 6;

  // prologue: stage tile 0 into buf 0, drain, preload ph0 fragments
#pragma unroll
  for (int g = 0; g < 4; ++g) {
    gload16(Ag + g * r8, Al + g * 1024);
    gload16(Bg + g * r8, Bl + g * 1024);
  }
  asm volatile("s_waitcnt vmcnt(0)" ::: "memory");
  __builtin_amdgcn_s_barrier();
  short8 aX[4], aY[4], bX[4], bY[4];
  LDA_(aX, (const char*)Alds, 0, pc0);
  LDB_(bX, (const char*)Blds, pc0);

  for (int t = 0; t < nt; ++t) {
    const int cur = t & 1;
    const char* Ab = (const char*)Alds + cur * 32768;
    const char* Bb = (const char*)Blds + cur * 32768;
    const char* An = (const char*)Alds + (cur ^ 1) * 32768;
    const char* Bn = (const char*)Blds + (cur ^ 1) * 32768;
    char* Aln = Al + (cur ^ 1) * 32768;
    char* Bln = Bl + (cur ^ 1) * 32768;
    const bool nx = (t + 1 < nt);
    const long long ko = (long long)(t + 1) * 64;

    // ---- ph0: MFMA(aX,bX)->acc0 ; stage next-B ; prefetch aY (ph1)
    if (nx) {
#pragma unroll
      for (int g = 0; g < 4; ++g) gload16(Bg + ko + g * r8, Bln + g * 1024);
    }
    LDA_(aY, Ab, 1, pc0);
    asm volatile("s_waitcnt lgkmcnt(4)" ::: "memory");   // aX,bX done; aY in flight
    __builtin_amdgcn_sched_barrier(0);
    __builtin_amdgcn_s_barrier();
    MM_(acc0, aX, bX);

    // ---- ph1: MFMA(aY,bX)->acc1 ; stage next-A ; prefetch aX,bY (ph2)
    if (nx) {
#pragma unroll
      for (int g = 0; g < 4; ++g) gload16(Ag + ko + g * r8, Aln + g * 1024);
    }
    LDA_(aX, Ab, 0, pc1);
    LDB_(bY, Bb, pc1);
    asm volatile("s_waitcnt lgkmcnt(8)" ::: "memory");   // aY done; aX,bY in flight
    __builtin_amdgcn_sched_barrier(0);
    __builtin_amdgcn_s_barrier();
    MM_(acc1, aY, bX);

    // ---- ph2: MFMA(aX,bY)->acc0 ; prefetch aY (ph3)
    LDA_(aY, Ab, 1, pc1);
    asm volatile("s_waitcnt lgkmcnt(4)" ::: "memory");   // aX,bY done; aY in flight
    __builtin_amdgcn_sched_barrier(0);
    __builtin_amdgcn_s_barrier();
    MM_(acc0, aX, bY);

    // ---- ph3: boundary sync, then MFMA(aY,bY)->acc1 with next-tile reads under it
    asm volatile("s_waitcnt lgkmcnt(0)" ::: "memory");   // aY done (all reads drained)
    if (nx) {
      asm volatile("s_waitcnt vmcnt(0)" ::: "memory");   // own 8 stage loads landed
    }
    __builtin_amdgcn_sched_barrier(0);
    __builtin_amdgcn_s_barrier();                        // ALL waves: reads drained + stages landed
    if (nx) {
      LDA_(aX, An, 0, pc0);                              // next-tile ph0 frags, hide under MFMA
      LDB_(bX, Bn, pc0);
    }
    MM_(acc1, aY, bY);
  }
}

// fused QKV: A = Wt rows o in [0,1536) (Wq|Wk|Wv stacked), B = Hn[z], K=512.
__global__ __launch_bounds__(512, 2) void gemm_qkv(
    const u16* __restrict__ Wt, const u16* __restrict__ Hn,
    u16* __restrict__ Qb, u16* __restrict__ Kb, u16* __restrict__ Vt,
    const float* __restrict__ bq, const float* __restrict__ bk,
    const float* __restrict__ bv) {
  __shared__ u16 Alds[2 * 256 * 64];
  __shared__ u16 Blds[2 * 256 * 64];
  const uint3 bid = remap_xcd();
  const int z = bid.z;
  const u16* B = Hn + (size_t)z * ((size_t)N_ * C_);
  const int m0 = bid.y * 256;    // o in [0,1536)
  const int n0 = bid.x * 256;    // n
  f32x4 acc0[4][4] = {};
  f32x4 acc1[4][4] = {};
  gemm_core256(Wt, B, 512, m0, n0, Alds, Blds, acc0, acc1);

  const int lane = threadIdx.x & 63, wid = threadIdx.x >> 6;
  const int wm = wid >> 2, wn = wid & 3;
  const int mat = m0 >> 9;       // 0:Q 1:K 2:V (block-uniform)
  const float* bias = (mat == 0) ? bq : (mat == 1) ? bk : bv;
  u16* O  = ((mat == 0) ? Qb : Kb) + (size_t)z * ((size_t)N_ * C_);
  u16* Vz = Vt + (size_t)z * ((size_t)N_ * C_);
#pragma unroll
  for (int i = 0; i < 8; ++i) {
    const int rowg = m0 + wm * 128 + i * 16 + ((lane >> 4) * 4);
    const int o = rowg & 511;
    const float4 bvv = *(const float4*)(bias + o);
#pragma unroll
    for (int j = 0; j < 4; ++j) {
      const int colg = n0 + wn * 64 + j * 16 + (lane & 15);
      const f32x4 v = (i < 4) ? acc0[i][j] : acc1[i - 4][j];
      if (mat < 2) {
        ushort4 st;
        st.x = f2bf(v[0] + bvv.x);
        st.y = f2bf(v[1] + bvv.y);
        st.z = f2bf(v[2] + bvv.z);
        st.w = f2bf(v[3] + bvv.w);
        *(ushort4*)(O + (size_t)colg * 512 + o) = st;
      } else {
        Vz[(size_t)(o + 0) * N_ + colg] = f2bf(v[0] + bvv.x);
        Vz[(size_t)(o + 1) * N_ + colg] = f2bf(v[1] + bvv.y);
        Vz[(size_t)(o + 2) * N_ + colg] = f2bf(v[2] + bvv.z);
        Vz[(size_t)(o + 3) * N_ + colg] = f2bf(v[3] + bvv.w);
      }
    }
  }
}

// S-GEMM + exp2 epilogue: P[n][m] = exp2(K.Q * kLog2Scale), bf16 (unnormalized, no max
// subtraction: |s·log2scale| <~ 12 -> exp2 <= 4096, f32/bf16-safe).
// Per-block partial row-sums -> Psum[z][slot][n], slot = (m0>>7)+wm (each written by
// exactly ONE wave -> deterministic, no atomics). PV divides by the 8-slot sum.
__global__ __launch_bounds__(512, 2) void gemm_s(
    const u16* __restrict__ Kb, const u16* __restrict__ Qb,
    u16* __restrict__ P, float* __restrict__ Psum) {
  __shared__ u16 Alds[2 * 256 * 64];
  __shared__ u16 Blds[2 * 256 * 64];
  const uint3 bid = remap_xcd();
  const int z = bid.z;
  const u16* A = Kb + (size_t)z * ((size_t)N_ * C_);   // rows m
  const u16* B = Qb + (size_t)z * ((size_t)N_ * C_);   // rows n
  u16*       O = P  + (size_t)z * ((size_t)N_ * N_);
  const int m0 = bid.y * 256, n0 = bid.x * 256;
  f32x4 acc0[4][4] = {};
  f32x4 acc1[4][4] = {};
  gemm_core256(A, B, 512, m0, n0, Alds, Blds, acc0, acc1);

  const int lane = threadIdx.x & 63, wid = threadIdx.x >> 6;
  const int wm = wid >> 2, wn = wid & 3;
  float psum[4] = {0.f, 0.f, 0.f, 0.f};
#pragma unroll
  for (int i = 0; i < 8; ++i) {
    const int rowg = m0 + wm * 128 + i * 16 + ((lane >> 4) * 4);   // m
#pragma unroll
    for (int j = 0; j < 4; ++j) {
      const int colg = n0 + wn * 64 + j * 16 + (lane & 15);        // n
      const f32x4 v = (i < 4) ? acc0[i][j] : acc1[i - 4][j];
      const float p0 = __builtin_exp2f(v[0] * kLog2Scale);
      const float p1 = __builtin_exp2f(v[1] * kLog2Scale);
      const float p2 = __builtin_exp2f(v[2] * kLog2Scale);
      const float p3 = __builtin_exp2f(v[3] * kLog2Scale);
      psum[j] += (p0 + p1) + (p2 + p3);
      ushort4 st;
      st.x = f2bf(p0); st.y = f2bf(p1); st.z = f2bf(p2); st.w = f2bf(p3);
      *(ushort4*)(O + (size_t)colg * 1024 + rowg) = st;
    }
  }
  // reduce over lane>>4 (4 lanes hold disjoint m-chunks of same n) -> wave partial
  const int slot = (m0 >> 7) + wm;             // 0..7
  float* Ps = Psum + ((size_t)z * 8 + slot) * N_;
#pragma unroll
  for (int j = 0; j < 4; ++j) {
    float r = psum[j];
    r += __shfl_xor(r, 16);
    r += __shfl_xor(r, 32);
    if (lane < 16) Ps[n0 + wn * 64 + j * 16 + lane] = r;
  }
}

// PV: H2[n][c] = (P[n][:] . V[:][c]) / rowsum(P[n]);  A=Vt (rows c), B=P (rows n), K=1024.
__global__ __launch_bounds__(512, 2) void gemm_pv(
    const u16* __restrict__ Vt, const u16* __restrict__ P,
    const float* __restrict__ Psum, u16* __restrict__ H2) {
  __shared__ u16 Alds[2 * 256 * 64];
  __shared__ u16 Blds[2 * 256 * 64];
  const uint3 bid = remap_xcd();
  const int z = bid.z;
  const u16* A = Vt + (size_t)z * ((size_t)N_ * C_);
  const u16* B = P  + (size_t)z * ((size_t)N_ * N_);
  u16*       O = H2 + (size_t)z * ((size_t)N_ * C_);
  const int m0 = bid.y * 256, n0 = bid.x * 256;   // m0: c, n0: n
  f32x4 acc0[4][4] = {};
  f32x4 acc1[4][4] = {};
  gemm_core256(A, B, 1024, m0, n0, Alds, Blds, acc0, acc1);

  const int lane = threadIdx.x & 63, wid = threadIdx.x >> 6;
  const int wm = wid >> 2, wn = wid & 3;
  const float* Ps = Psum + (size_t)z * 8 * N_;
  float inv[4];
#pragma unroll
  for (int j = 0; j < 4; ++j) {
    const int colg = n0 + wn * 64 + j * 16 + (lane & 15);
    float s = 0.f;
#pragma unroll
    for (int k = 0; k < 8; ++k) s += Ps[k * N_ + colg];
    inv[j] = 1.0f / s;
  }
#pragma unroll
  for (int i = 0; i < 8; ++i) {
    const int rowg = m0 + wm * 128 + i * 16 + ((lane >> 4) * 4);   // c
#pragma unroll
    for (int j = 0; j < 4; ++j) {
      const int colg = n0 + wn * 64 + j * 16 + (lane & 15);        // n
      const f32x4 v = (i < 4) ? acc0[i][j] : acc1[i - 4][j];
      ushort4 st;
      st.x = f2bf(v[0] * inv[j]);
      st.y = f2bf(v[1] * inv[j]);
      st.z = f2bf(v[2] * inv[j]);
      st.w = f2bf(v[3] * inv[j]);
      *(ushort4*)(O + (size_t)colg * 512 + rowg) = st;
    }
  }
}

// final: D[n][o] = sum_c H2[n][c]*Wnt[o][c]; out[b][o][n] = x + D + bn[o]  (fp32)
__global__ __launch_bounds__(512, 2) void gemm_bt_final(
    const u16* __restrict__ A, const u16* __restrict__ Bw,
    const float* __restrict__ x, const float* __restrict__ bn,
    float* __restrict__ Out, int Ktot) {
  __shared__ u16 Alds[2 * 256 * 64];
  __shared__ u16 Blds[2 * 256 * 64];
  const uint3 bid = remap_xcd();
  const int z = bid.z;
  const u16*   Ab = A + (size_t)z * ((size_t)N_ * C_);
  const float* xb = x + (size_t)z * ((size_t)C_ * N_);
  float*       Ob = Out + (size_t)z * ((size_t)C_ * N_);
  const int m0 = bid.y * 256, n0 = bid.x * 256;
  f32x4 acc0[4][4] = {};
  f32x4 acc1[4][4] = {};
  gemm_core256(Ab, Bw, Ktot, m0, n0, Alds, Blds, acc0, acc1);

  const int lane = threadIdx.x & 63, wid = threadIdx.x >> 6;
  const int wm = wid >> 2, wn = wid & 3;
#pragma unroll
  for (int i = 0; i < 8; ++i) {
    const int rowg = m0 + wm * 128 + i * 16 + ((lane >> 4) * 4);   // n
#pragma unroll
    for (int j = 0; j < 4; ++j) {
      const int colg = n0 + wn * 64 + j * 16 + (lane & 15);        // o
      const float bc = bn[colg];
      const size_t off = (size_t)colg * N_ + rowg;
      const float4 xv = *(const float4*)(xb + off);
      const f32x4 v = (i < 4) ? acc0[i][j] : acc1[i - 4][j];
      float4 ov;
      ov.x = xv.x + v[0] + bc;
      ov.y = xv.y + v[1] + bc;
      ov.z = xv.z + v[2] + bc;
      ov.w = xv.w + v[3] + bc;
      *(float4*)(Ob + off) = ov;
    }
  }
}

__global__ void sentinel_kernel(float* out, int n, float v) {
  const int i = blockIdx.x * blockDim.x + threadIdx.x;
  if (i < n) out[i] = v;
}

extern "C" void kernel_launch(void* const* d_in, const int* in_sizes, int n_in,
                              void* d_out, int out_size, void* d_ws, size_t ws_size,
                              hipStream_t stream) {
  const float* x  = (const float*)d_in[0];
  const float* Wq = (const float*)d_in[1];
  const float* bq = (const float*)d_in[2];
  const float* Wk = (const float*)d_in[3];
  const float* bk = (const float*)d_in[4];
  const float* Wv = (const float*)d_in[5];
  const float* bv = (const float*)d_in[6];
  const float* Wn = (const float*)d_in[7];
  const float* bn = (const float*)d_in[8];
  float* out = (float*)d_out;

  char* ws = (char*)d_ws;
  size_t off = 0;
  u16* Wt = (u16*)(ws + off);      off += (size_t)4 * 512 * 512 * 2;   // bf16 W^T x4 (Q|K|V|N)
  const size_t bnc = (size_t)B_ * N_ * C_;
  u16* Hn = (u16*)(ws + off); off += bnc * 2;          // [b][n][c]
  u16* Qb = (u16*)(ws + off); off += bnc * 2;          // [b][n][c]
  u16* Kb = (u16*)(ws + off); off += bnc * 2;          // [b][m][c]
  u16* Vt = (u16*)(ws + off); off += bnc * 2;          // [b][c][m]
  u16* P  = (u16*)(ws + off); off += (size_t)B_ * N_ * N_ * 2;  // [b][n][m] exp2 bf16
  u16* H2 = (u16*)(ws + off); off += bnc * 2;          // [b][n][c]
  float* Psum = (float*)(ws + off); off += (size_t)B_ * 8 * N_ * 4;  // partial row sums

  if (ws_size < off) {
    const float v = 1.0e6f + (float)(ws_size >> 20);   // absmax ~ 1e6+MB -> diagnosable
    sentinel_kernel<<<(out_size + 255) / 256, 256, 0, stream>>>(out, out_size, v);
    return;
  }

  wt_kernel<<<dim3(8, 8, 4), 256, 0, stream>>>(Wq, Wk, Wv, Wn, Wt);
  gn_fused<<<B_ * G_, 256, 0, stream>>>(x, Hn);

  // fused QKV: o-rows [0,1536) of Wt vs Hn; writes Qb[n][o], Kb[n][o], Vt[o][n]+biases
  gemm_qkv<<<dim3(4, 6, B_), 512, 0, stream>>>(Wt, Hn, Qb, Kb, Vt, bq, bk, bv);
  // S + exp2 epilogue + partial row-sums
  gemm_s<<<dim3(4, 4, B_), 512, 0, stream>>>(Kb, Qb, P, Psum);
  // PV + normalize epilogue
  gemm_pv<<<dim3(4, 2, B_), 512, 0, stream>>>(Vt, P, Psum, H2);
  // out[o][n] = x + H2·Wn^T + bn
  gemm_bt_final<<<dim3(2, 4, B_), 512, 0, stream>>>(H2, Wt + 3 * 262144, x, bn, out, 512);
}